// Round 26
// baseline (2976.228 us; speedup 1.0000x reference)
//
#include <hip/hip_runtime.h>
#include <math.h>

#define NB 64
#define ND 2048
#define NE 512
#define NM 25
#define NOUT 4096
#define NHEADS 8
#define NDH 64
#define NS 64
#define NITER 50
#define NKSYN 2560
#define PRED_TOTAL (NB * NOUT * NITER)   /* 13107200 */

typedef unsigned short bf16_t;
typedef __attribute__((ext_vector_type(8))) short short8;
typedef __attribute__((ext_vector_type(4))) float f32x4;

__device__ __forceinline__ float sigm(float x) { return 1.f / (1.f + expf(-x)); }

__device__ __forceinline__ bf16_t f2bf(float f) {
    unsigned u = __float_as_uint(f);
    unsigned r = (u + 0x7FFFu + ((u >> 16) & 1u)) >> 16;
    return (bf16_t)r;
}
__device__ __forceinline__ float bf2f(bf16_t h) {
    return __uint_as_float(((unsigned)h) << 16);
}

__device__ __forceinline__ float wredsum(float v) {
#pragma unroll
    for (int o = 32; o; o >>= 1) v += __shfl_xor(v, o);
    return v;
}
__device__ __forceinline__ float wredmax(float v) {
#pragma unroll
    for (int o = 32; o; o >>= 1) v = fmaxf(v, __shfl_xor(v, o));
    return v;
}

template <int OP>
__device__ __forceinline__ float blockReduce(float v, float* red) {
    const int tid = threadIdx.x, lane = tid & 63, wid = tid >> 6;
    v = (OP == 0) ? wredsum(v) : wredmax(v);
    __syncthreads();
    if (lane == 0) red[wid] = v;
    __syncthreads();
    if (tid == 0) {
        const int nw = blockDim.x >> 6;
        float r = red[0];
        for (int w = 1; w < nw; ++w) r = (OP == 0) ? r + red[w] : fmaxf(r, red[w]);
        red[0] = r;
    }
    __syncthreads();
    return red[0];
}

// ---------------- per-step kernels (4 dispatches/step) ----------------

// K1: front(t) on blocks [0,256) + sync_o(t-1) on blocks [256,264). 512 thr.
__global__ __launch_bounds__(512) void k_fo(
        const float* __restrict__ actT, bf16_t* __restrict__ actB,
        float* __restrict__ aA, float* __restrict__ bA,
        const float* __restrict__ r_a,
        const int* __restrict__ ial, const int* __restrict__ iar,
        const bf16_t* __restrict__ W_qqb, const float* __restrict__ b_qq,
        const bf16_t* __restrict__ kvp,
        float* __restrict__ aO, float* __restrict__ bO,
        const float* __restrict__ r_o,
        const int* __restrict__ iol, const int* __restrict__ ior,
        bf16_t* __restrict__ syncB,
        int doFront, int doOut, int it) {
    __shared__ float lds[1280];
    const int bid = blockIdx.x;
    const int t = threadIdx.x;
    const int lane = t & 63, wv = t >> 6;

    if (bid >= 256) {
        // ---- sync_o(t-1): 8 blocks, i-slice sb*64, all 64 b ----
        if (!doOut) return;
        const int sb = bid - 256;
        const int itO = it - 1;
        const int srcO = itO & 1, dstO = srcO ^ 1;
#pragma unroll
        for (int c = 0; c < 8; ++c) {
            const int idx = t + c * 512;
            const int il = idx >> 6, bb = idx & 63;
            const int i = sb * 64 + il;
            const float pl = actT[iol[i] * NB + bb];
            const float prr = actT[ior[i] * NB + bb];
            const float r = r_o[i];
            const float aN = r * aO[srcO * 32768 + i * NB + bb] + pl * prr;
            const float bN = r * bO[srcO * 32768 + i * NB + bb] + 1.f;
            aO[dstO * 32768 + i * NB + bb] = aN;
            bO[dstO * 32768 + i * NB + bb] = bN;
            syncB[(size_t)bb * NE + i] = f2bf(aN * rsqrtf(bN));
        }
        return;
    }

    // ---- front(t) ----
    if (!doFront) return;
    float* syncS = lds;
    float* partK = lds + 512;
    float* qhS = lds + 1024;
    float* attnS = lds + 1152;
    const int jt = bid >> 6, b = bid & 63;
    const int src = it & 1, dst = src ^ 1;
    {
        const int i = t;
        const float pl = actT[ial[i] * NB + b];
        const float prr = actT[iar[i] * NB + b];
        const float r = r_a[i];
        const float aN = r * aA[src * 32768 + b * NE + i] + pl * prr;
        const float bN = r * bA[src * 32768 + b * NE + i] + 1.f;
        if (jt == 0) {
            aA[dst * 32768 + b * NE + i] = aN;
            bA[dst * 32768 + b * NE + i] = bN;
        }
        syncS[i] = aN * rsqrtf(bN);
    }
    __syncthreads();
    {
        const int g = t >> 7, l = t & 127;
        const int j = jt * 128 + l;
        float acc = 0.f;
        const int kk0 = g * 128;
#pragma unroll 4
        for (int k = kk0; k < kk0 + 128; ++k)
            acc = fmaf(syncS[k], bf2f(W_qqb[k * NE + j]), acc);
        partK[g * 128 + l] = acc;
    }
    __syncthreads();
    if (t < 128) {
        qhS[t] = b_qq[jt * 128 + t] + partK[t] + partK[128 + t] + partK[256 + t] + partK[384 + t];
    }
    __syncthreads();
    if (wv < 2) {
        const int h = jt * 2 + wv, s = lane;
        const bf16_t* kpp = kvp + ((size_t)(b * NS + s) * 1024 + h * NDH);
        float sc = 0.f;
#pragma unroll 8
        for (int d = 0; d < NDH; ++d) sc = fmaf(qhS[wv * 64 + d], bf2f(kpp[d]), sc);
        sc *= 0.125f;
        const float mxv = wredmax(sc);
        const float ev = expf(sc - mxv);
        const float sm = wredsum(ev);
        attnS[wv * 64 + s] = ev / sm;
    }
    __syncthreads();
    if (wv < 2) {
        const int h = jt * 2 + wv, d = lane;
        const bf16_t* vpp = kvp + ((size_t)(b * NS) * 1024 + NE + h * NDH + d);
        float o = 0.f;
#pragma unroll 8
        for (int s2 = 0; s2 < NS; ++s2) o = fmaf(attnS[wv * 64 + s2], bf2f(vpp[(size_t)s2 * 1024]), o);
        actB[(size_t)b * NKSYN + h * NDH + d] = f2bf(o);
    }
}

// K2: syn MFMA GEMM(t) kp=4 on blocks [0,256) + out MFMA GEMM(t-1) on [256,320). 256 thr.
__global__ __launch_bounds__(256) void k_gf(
        const bf16_t* __restrict__ actB, const bf16_t* __restrict__ bpack,
        float* __restrict__ part_syn,
        const bf16_t* __restrict__ syncB, const bf16_t* __restrict__ outwp,
        const float* __restrict__ out_b, float* __restrict__ predRaw,
        int doGemm, int doOutM) {
    const int bid = blockIdx.x;
    const int t = threadIdx.x;
    if (bid < 256) {
        if (!doGemm) return;
        const int kp = bid >> 6, jt = bid & 63;
        const int l = t & 63;
        const int wv = t >> 6;
        const int b0 = wv * 16;
        const int row = b0 + (l & 15);
        const int kgrp = l >> 4;
        f32x4 acc[4];
#pragma unroll
        for (int js = 0; js < 4; ++js) acc[js] = (f32x4){0.f, 0.f, 0.f, 0.f};
        const int ks0 = kp * 20;
#pragma unroll 2
        for (int ks = 0; ks < 20; ++ks) {
            const int kk = (ks0 + ks) * 32;
            const short8 av = *(const short8*)(actB + (size_t)row * NKSYN + kk + kgrp * 8);
#pragma unroll
            for (int js = 0; js < 4; ++js) {
                const short8 bv = *(const short8*)(bpack +
                    ((((size_t)(jt * 4 + js)) * 80 + ks0 + ks) * 64 + l) * 8);
                acc[js] = __builtin_amdgcn_mfma_f32_16x16x32_bf16(av, bv, acc[js], 0, 0, 0);
            }
        }
#pragma unroll
        for (int js = 0; js < 4; ++js) {
#pragma unroll
            for (int r = 0; r < 4; ++r) {
                const int b = b0 + kgrp * 4 + r;
                const int j = jt * 64 + js * 16 + (l & 15);
                part_syn[((size_t)(kp * NB + b)) * NOUT + j] = acc[js][r];
            }
        }
    } else {
        // ---- out GEMM(t-1): predRaw[b][j] = syncB @ out_w + out_b. full K=512.
        if (!doOutM) return;
        const int nt = bid - 256;
        const int l = t & 63;
        const int w = t >> 6;
        const int row0 = w * 16;
        const int row = row0 + (l & 15);
        const int kgrp = l >> 4;
        f32x4 acc[4];
#pragma unroll
        for (int js = 0; js < 4; ++js) acc[js] = (f32x4){0.f, 0.f, 0.f, 0.f};
#pragma unroll 2
        for (int ks = 0; ks < 16; ++ks) {
            const short8 av = *(const short8*)(syncB + (size_t)row * NE + ks * 32 + kgrp * 8);
#pragma unroll
            for (int js = 0; js < 4; ++js) {
                const short8 bv8 = *(const short8*)(outwp +
                    ((((size_t)(nt * 4 + js)) * 16 + ks) * 64 + l) * 8);
                acc[js] = __builtin_amdgcn_mfma_f32_16x16x32_bf16(av, bv8, acc[js], 0, 0, 0);
            }
        }
#pragma unroll
        for (int js = 0; js < 4; ++js) {
#pragma unroll
            for (int r = 0; r < 4; ++r) {
                const int b = row0 + kgrp * 4 + r;
                const int j = nt * 64 + js * 16 + (l & 15);
                predRaw[(size_t)b * NOUT + j] = acc[js][r] + out_b[j];
            }
        }
    }
}

// K3: glu on blocks [0,256) + final(t-1) on blocks [256,320). 512 thr.
__global__ __launch_bounds__(512) void k_glu(const float* __restrict__ part,
                                             const float* __restrict__ sbe,
                                             float* __restrict__ trace2,
                                             float* __restrict__ statsPart, int pos,
                                             const float* __restrict__ predRaw,
                                             float* __restrict__ out,
                                             float* __restrict__ predTemp,
                                             int doGlu, int doFinal, int tt, int tmode) {
    __shared__ float red[8];
    const int bid = blockIdx.x;
    const int t = threadIdx.x;
    if (bid < 256) {
        if (!doGlu) return;
        const int b = bid >> 2, q = bid & 3;
        const int n = q * 512 + t;
        float ya = sbe[n], yb = sbe[n + ND];
#pragma unroll
        for (int kp = 0; kp < 4; ++kp) {
            ya += part[((size_t)(kp * NB + b)) * NOUT + n];
            yb += part[((size_t)(kp * NB + b)) * NOUT + n + ND];
        }
        const float g = ya * sigm(yb);
        trace2[((size_t)pos * ND + n) * NB + b] = g;     // raw (normalized by k_nlm)
        const float s = blockReduce<0>(g, red);
        const float ss = blockReduce<0>(g * g, red);
        if (t == 0) {
            statsPart[bid * 2 + 0] = s;
            statsPart[bid * 2 + 1] = ss;
        }
    } else {
        if (!doFinal) return;
        const int b = bid - 256;
        float pr[8];
        float lmax = -1e30f;
#pragma unroll
        for (int c = 0; c < 8; ++c) {
            const int j = t + c * 512;
            const float v = predRaw[(size_t)b * NOUT + j];
            pr[c] = v;
            lmax = fmaxf(lmax, v);
        }
        const float mx = blockReduce<1>(lmax, red);
        float ls = 0.f;
#pragma unroll
        for (int c = 0; c < 8; ++c) ls += expf(pr[c] - mx);
        const float se = blockReduce<0>(ls, red);
        const float logZ = mx + logf(se);
        float le = 0.f;
#pragma unroll
        for (int c = 0; c < 8; ++c) { const float lp = pr[c] - logZ; le += expf(lp) * lp; }
        const float ent = blockReduce<0>(le, red);
        const float ne = -ent * 0.12022458674074694f;  // 1/ln(4096)
        if (tmode) {
#pragma unroll
            for (int c = 0; c < 8; ++c)
                predTemp[((size_t)b * NITER + tt) * NOUT + t + c * 512] = pr[c];
        } else {
#pragma unroll
            for (int c = 0; c < 8; ++c) {
                const int j = t + c * 512;
                out[((size_t)b * NOUT + j) * NITER + tt] = pr[c];
            }
        }
        if (t == 0) {
            out[PRED_TOTAL + b * 100 + tt] = ne;
            out[PRED_TOTAL + b * 100 + 50 + tt] = 1.f - ne;
        }
    }
}

// K4: per-neuron NLMs, block = ONE neuron (grid 2048 x 256).
__global__ __launch_bounds__(256) void k_nlm(float* __restrict__ trace2,
                                             const bf16_t* __restrict__ bw1t,
                                             const float* __restrict__ b1,
                                             const float* __restrict__ w2t,
                                             const float* __restrict__ b2,
                                             const float* __restrict__ statsPart,
                                             const float* __restrict__ ln_g,
                                             const float* __restrict__ ln_b,
                                             float* __restrict__ actT,
                                             bf16_t* __restrict__ actB, int pos) {
    __shared__ float sacc[32][64];
    __shared__ float pz[2][2][64];
    const int b = threadIdx.x & 63;
    const int g = __builtin_amdgcn_readfirstlane(threadIdx.x >> 6);
    const int n = blockIdx.x;
    const int hh0 = g * 16;
    float ssum = 0.f, ssq = 0.f;
#pragma unroll
    for (int q = 0; q < 4; ++q) {
        ssum += statsPart[(b * 4 + q) * 2 + 0];
        ssq  += statsPart[(b * 4 + q) * 2 + 1];
    }
    const float mean = ssum * (1.f / ND);
    const float rs = rsqrtf(ssq * (1.f / ND) - mean * mean + 1e-5f);

    float trv[NM];
    float trNew;
    {
        int phys = (pos + 1 < NM) ? pos + 1 : 0;
#pragma unroll
        for (int m = 0; m < NM - 1; ++m) {
            trv[m] = trace2[((size_t)phys * ND + n) * NB + b];
            phys = (phys + 1 < NM) ? phys + 1 : 0;
        }
        const float raw = trace2[((size_t)pos * ND + n) * NB + b];
        trNew = (raw - mean) * rs * ln_g[n] + ln_b[n];
        trv[NM - 1] = trNew;
    }
    __syncthreads();   // all waves hold raw before the owner write
    if (g == 0) trace2[((size_t)pos * ND + n) * NB + b] = trNew;

    float acc[16];
    {
        const float* brow = b1 + n * 64 + hh0;
#pragma unroll
        for (int q = 0; q < 16; ++q) acc[q] = brow[q];
    }
#pragma unroll
    for (int m = 0; m < NM; ++m) {
        const float tr = trv[m];
        const unsigned* wrow = (const unsigned*)(bw1t + ((size_t)n * NM + m) * 64 + hh0);
#pragma unroll
        for (int q = 0; q < 8; ++q) {
            const unsigned u = wrow[q];
            const float w0 = __uint_as_float(u << 16);
            const float w1 = __uint_as_float(u & 0xffff0000u);
            acc[2 * q + 0] = fmaf(tr, w0, acc[2 * q + 0]);
            acc[2 * q + 1] = fmaf(tr, w1, acc[2 * q + 1]);
        }
    }
    if (g >= 2) {
#pragma unroll
        for (int q = 0; q < 16; ++q) sacc[hh0 - 32 + q][b] = acc[q];
    }
    __syncthreads();
    if (g < 2) {
        const float* w2r = w2t + n * 64;
        float z0p = 0.f, z1p = 0.f;
#pragma unroll
        for (int q = 0; q < 16; ++q) {
            const int i = hh0 + q;
            const float hv = acc[q] * sigm(sacc[i][b]);
            z0p = fmaf(hv, w2r[i], z0p);
            z1p = fmaf(hv, w2r[32 + i], z1p);
        }
        pz[0][g][b] = z0p;
        pz[1][g][b] = z1p;
    }
    __syncthreads();
    if (g == 0) {
        const float z0 = b2[n * 2 + 0] + pz[0][0][b] + pz[0][1][b];
        const float z1 = b2[n * 2 + 1] + pz[1][0][b] + pz[1][1][b];
        const float val = z0 * sigm(z1);
        actT[n * NB + b] = val;
        actB[(size_t)b * NKSYN + NE + n] = f2bf(val);
    }
}

// ---------------- one-time precompute kernels ----------------

__global__ __launch_bounds__(256) void k_p0(const float* __restrict__ dec_a,
                                            const float* __restrict__ dec_o,
                                            const float* __restrict__ q_b,
                                            const float* __restrict__ wq,
                                            const float* __restrict__ bq,
                                            float* __restrict__ r_a, float* __restrict__ r_o,
                                            float* __restrict__ b_qq) {
    const int t = threadIdx.x;
    if (blockIdx.x == 0) {
        for (int i = t; i < NE; i += 256) {
            r_a[i] = expf(-fminf(fmaxf(dec_a[i], 0.f), 15.f));
            r_o[i] = expf(-fminf(fmaxf(dec_o[i], 0.f), 15.f));
        }
        return;
    }
    __shared__ float partial[4][64];
    const int c = (blockIdx.x - 1) * 64 + (t & 63);
    const int kg = t >> 6;
    float acc = 0.f;
#pragma unroll 4
    for (int k = kg * 128; k < kg * 128 + 128; ++k)
        acc = fmaf(q_b[k], wq[k * NE + c], acc);
    partial[kg][t & 63] = acc;
    __syncthreads();
    if (t < 64) {
        const int cc = (blockIdx.x - 1) * 64 + t;
        b_qq[cc] = bq[cc] + partial[0][t] + partial[1][t] + partial[2][t] + partial[3][t];
    }
}

// Generic B-fragment pack: src [K x ld] fp32 -> MFMA frag order.
__global__ __launch_bounds__(256) void k_packB(const float* __restrict__ src,
                                               int ld, int nbj, int ksgs,
                                               bf16_t* __restrict__ dst) {
    __shared__ float tile[32][65];
    const int ksg = blockIdx.x / nbj;
    const int bj = blockIdx.x % nbj;
    const int k0 = ksg * 32, j0 = bj * 64;
    for (int i = threadIdx.x; i < 2048; i += 256) {
        const int kk = i >> 6, jj = i & 63;
        tile[kk][jj] = src[(size_t)(k0 + kk) * ld + j0 + jj];
    }
    __syncthreads();
    for (int i = threadIdx.x; i < 2048; i += 256) {
        const int j16 = i >> 9;
        const int ii = i & 511;
        const int e = ii & 7, l = ii >> 3;
        const int kk = (l >> 4) * 8 + e;
        const int jj = j16 * 16 + (l & 15);
        dst[(((size_t)(bj * 4 + j16) * ksgs + ksg) * 64) * 8 + ii] = f2bf(tile[kk][jj]);
    }
}

// woSyn = wo @ syn_w[0:512] via MFMA. grid 512 (mt 8 x nt 64) x 256. fp32 out.
__global__ __launch_bounds__(256, 2) void k_woSynM(const bf16_t* __restrict__ bwo,
                                                   const bf16_t* __restrict__ synw0p,
                                                   float* __restrict__ woSyn) {
    const int mt = blockIdx.x >> 6, nt = blockIdx.x & 63;
    const int l = threadIdx.x & 63;
    const int w = threadIdx.x >> 6;
    const int row0 = mt * 64 + w * 16;
    const int row = row0 + (l & 15);
    const int kgrp = l >> 4;
    f32x4 acc[4];
#pragma unroll
    for (int js = 0; js < 4; ++js) acc[js] = (f32x4){0.f, 0.f, 0.f, 0.f};
#pragma unroll 2
    for (int ks = 0; ks < 16; ++ks) {
        const short8 av = *(const short8*)(bwo + (size_t)row * NE + ks * 32 + kgrp * 8);
#pragma unroll
        for (int js = 0; js < 4; ++js) {
            const short8 bv8 = *(const short8*)(synw0p +
                ((((size_t)(nt * 4 + js)) * 16 + ks) * 64 + l) * 8);
            acc[js] = __builtin_amdgcn_mfma_f32_16x16x32_bf16(av, bv8, acc[js], 0, 0, 0);
        }
    }
#pragma unroll
    for (int js = 0; js < 4; ++js) {
#pragma unroll
        for (int r = 0; r < 4; ++r) {
            const int e = row0 + kgrp * 4 + r;
            const int c = nt * 64 + js * 16 + (l & 15);
            woSyn[(size_t)e * NOUT + c] = acc[js][r];
        }
    }
}

// W_qq = q_w @ wq via MFMA -> bf16. grid 64 (mt 8 x nt 8) x 256.
__global__ __launch_bounds__(256, 2) void k_wqqM(const bf16_t* __restrict__ bqw,
                                                 const bf16_t* __restrict__ wqp,
                                                 bf16_t* __restrict__ W_qqb) {
    const int mt = blockIdx.x >> 3, nt = blockIdx.x & 7;
    const int l = threadIdx.x & 63;
    const int w = threadIdx.x >> 6;
    const int row0 = mt * 64 + w * 16;
    const int row = row0 + (l & 15);
    const int kgrp = l >> 4;
    f32x4 acc[4];
#pragma unroll
    for (int js = 0; js < 4; ++js) acc[js] = (f32x4){0.f, 0.f, 0.f, 0.f};
#pragma unroll 2
    for (int ks = 0; ks < 16; ++ks) {
        const short8 av = *(const short8*)(bqw + (size_t)row * NE + ks * 32 + kgrp * 8);
#pragma unroll
        for (int js = 0; js < 4; ++js) {
            const short8 bv8 = *(const short8*)(wqp +
                ((((size_t)(nt * 4 + js)) * 16 + ks) * 64 + l) * 8);
            acc[js] = __builtin_amdgcn_mfma_f32_16x16x32_bf16(av, bv8, acc[js], 0, 0, 0);
        }
    }
#pragma unroll
    for (int js = 0; js < 4; ++js) {
#pragma unroll
        for (int r = 0; r < 4; ++r) {
            const int e = row0 + kgrp * 4 + r;
            const int c = nt * 64 + js * 16 + (l & 15);
            W_qqb[(size_t)e * NE + c] = f2bf(acc[js][r]);
        }
    }
}

// sbe: grid 64 x 256, 4-way k-split + LDS reduce.
__global__ __launch_bounds__(256) void k_sbe(const float* __restrict__ syn_b,
                                             const float* __restrict__ bo,
                                             const float* __restrict__ syn_w,
                                             float* __restrict__ sbe) {
    __shared__ float partial[4][64];
    const int c = blockIdx.x * 64 + (threadIdx.x & 63);
    const int kg = threadIdx.x >> 6;
    float acc = 0.f;
#pragma unroll 4
    for (int jp = kg * 128; jp < kg * 128 + 128; ++jp)
        acc = fmaf(bo[jp], syn_w[(size_t)jp * NOUT + c], acc);
    partial[kg][threadIdx.x & 63] = acc;
    __syncthreads();
    if (threadIdx.x < 64) {
        const int cc = blockIdx.x * 64 + threadIdx.x;
        sbe[cc] = syn_b[cc] + partial[0][threadIdx.x] + partial[1][threadIdx.x]
                + partial[2][threadIdx.x] + partial[3][threadIdx.x];
    }
}

__global__ __launch_bounds__(256) void k_cvt(const float* __restrict__ s,
                                             bf16_t* __restrict__ d) {
    const size_t i = (size_t)blockIdx.x * 256 + threadIdx.x;
    d[i] = f2bf(s[i]);
}

// Tiled fragment-pack of combined weights [woSyn rows<512; syn_w rows 512+].
__global__ __launch_bounds__(256) void k_bpack(const float* __restrict__ woSyn,
                                               const float* __restrict__ syn_w,
                                               bf16_t* __restrict__ bpack) {
    __shared__ float tile[32][65];
    const int ksg = blockIdx.x >> 6;
    const int bj = blockIdx.x & 63;
    const int k0 = ksg * 32, j0 = bj * 64;
    for (int i = threadIdx.x; i < 2048; i += 256) {
        const int kk = i >> 6, jj = i & 63;
        const int k = k0 + kk;
        tile[kk][jj] = (k < NE) ? woSyn[(size_t)k * NOUT + j0 + jj]
                                : syn_w[(size_t)k * NOUT + j0 + jj];
    }
    __syncthreads();
    for (int i = threadIdx.x; i < 2048; i += 256) {
        const int j16 = i >> 9;
        const int ii = i & 511;
        const int e = ii & 7, l = ii >> 3;
        const int kk = (l >> 4) * 8 + e;
        const int jj = j16 * 16 + (l & 15);
        bpack[(((size_t)(bj * 4 + j16) * 80 + ksg) * 64) * 8 + ii] = f2bf(tile[kk][jj]);
    }
}

// Pack [wk | wv] (512 x 1024) into MFMA B-fragment order. grid 256.
__global__ __launch_bounds__(256) void k_wkvpack(const float* __restrict__ wk,
                                                 const float* __restrict__ wv,
                                                 bf16_t* __restrict__ wkvpack) {
    __shared__ float tile[32][65];
    const int ksg = blockIdx.x >> 4;
    const int bj = blockIdx.x & 15;
    const int k0 = ksg * 32, j0 = bj * 64;
    for (int i = threadIdx.x; i < 2048; i += 256) {
        const int kk = i >> 6, jj = i & 63;
        const int k = k0 + kk, j = j0 + jj;
        tile[kk][jj] = (j < NE) ? wk[(size_t)k * NE + j] : wv[(size_t)k * NE + (j - NE)];
    }
    __syncthreads();
    for (int i = threadIdx.x; i < 2048; i += 256) {
        const int j16 = i >> 9;
        const int ii = i & 511;
        const int e = ii & 7, l = ii >> 3;
        const int kk = (l >> 4) * 8 + e;
        const int jj = j16 * 16 + (l & 15);
        wkvpack[(((size_t)(bj * 4 + j16) * 16 + ksg) * 64) * 8 + ii] = f2bf(tile[kk][jj]);
    }
}

__global__ __launch_bounds__(256) void k_init_trace2(const float* __restrict__ st,
                                                     float* __restrict__ trace2) {
    const int idx = blockIdx.x * 256 + threadIdx.x;
    const int n = (idx >> 6) & (ND - 1);
    const int m = idx >> 17;
    trace2[idx] = st[n * NM + m];
}

#define INIT_TOTAL (NB * ND + 8 * NB * NE)
__global__ __launch_bounds__(256) void k_init_state(const float* __restrict__ sa,
                                                    float* __restrict__ actT,
                                                    bf16_t* __restrict__ actB,
                                                    float* __restrict__ zeroBase) {
    const int idx = blockIdx.x * 256 + threadIdx.x;
    if (idx >= INIT_TOTAL) return;
    if (idx < NB * ND) {
        const int b = idx & 63, n = idx >> 6;
        actT[n * NB + b] = sa[n];
        actB[(size_t)b * NKSYN + NE + n] = f2bf(sa[n]);
    } else {
        zeroBase[idx - NB * ND] = 0.f;
    }
}

// k_p1a: kvn = LN(feats @ kv_w + kv_b) -> kvnB bf16 [token][e].
__global__ __launch_bounds__(512) void k_p1a(const float* __restrict__ x,
                                             const float* __restrict__ kv_w,
                                             const float* __restrict__ kv_b,
                                             const float* __restrict__ ln_g,
                                             const float* __restrict__ ln_b,
                                             bf16_t* __restrict__ kvnB) {
    __shared__ float kvT[NE][17];
    __shared__ float mS[16], rS[16];
    const int b = blockIdx.x >> 2, s0 = (blockIdx.x & 3) * 16;
    const int t = threadIdx.x;
    const int lane = t & 63, wvi = t >> 6;
    {
        float w[12];
#pragma unroll
        for (int c = 0; c < 12; ++c) w[c] = kv_w[c * NE + t];
        const float kb = kv_b[t];
#pragma unroll
        for (int tok = 0; tok < 16; ++tok) {
            float acc = kb;
#pragma unroll
            for (int c = 0; c < 12; ++c)
                acc = fmaf(x[b * 768 + c * 64 + s0 + tok], w[c], acc);
            kvT[t][tok] = acc;
        }
    }
    __syncthreads();
#pragma unroll
    for (int q = 0; q < 2; ++q) {
        const int tok = wvi * 2 + q;
        float s = 0.f, ss = 0.f;
#pragma unroll
        for (int i = 0; i < 8; ++i) {
            const float v = kvT[lane + 64 * i][tok];
            s += v; ss = fmaf(v, v, ss);
        }
        s = wredsum(s); ss = wredsum(ss);
        if (lane == 0) {
            const float mean = s * (1.f / NE);
            mS[tok] = mean;
            rS[tok] = rsqrtf(ss * (1.f / NE) - mean * mean + 1e-5f);
        }
    }
    __syncthreads();
    {
        const float g = ln_g[t], bb2 = ln_b[t];
#pragma unroll
        for (int tok = 0; tok < 16; ++tok) {
            const float kvn = (kvT[t][tok] - mS[tok]) * rS[tok] * g + bb2;
            kvnB[(size_t)(b * 64 + s0 + tok) * NE + t] = f2bf(kvn);
        }
    }
}

// k_p1b: MFMA GEMM [4096 tokens x 1024 (K|V) x 512] -> kvp bf16 [token][1024].
__global__ __launch_bounds__(256, 2) void k_p1b(const bf16_t* __restrict__ kvnB,
                                                const bf16_t* __restrict__ wkvpack,
                                                const float* __restrict__ bk,
                                                const float* __restrict__ bv,
                                                bf16_t* __restrict__ kvp) {
    const int mt = blockIdx.x >> 4, nt = blockIdx.x & 15;
    const int l = threadIdx.x & 63;
    const int wv = threadIdx.x >> 6;
    const int row0 = mt * 64 + wv * 16;
    const int row = row0 + (l & 15);
    const int kgrp = l >> 4;
    f32x4 acc[4];
#pragma unroll
    for (int js = 0; js < 4; ++js) acc[js] = (f32x4){0.f, 0.f, 0.f, 0.f};
#pragma unroll 2
    for (int ks = 0; ks < 16; ++ks) {
        const short8 av = *(const short8*)(kvnB + (size_t)row * NE + ks * 32 + kgrp * 8);
#pragma unroll
        for (int js = 0; js < 4; ++js) {
            const short8 bv8 = *(const short8*)(wkvpack +
                ((((size_t)(nt * 4 + js)) * 16 + ks) * 64 + l) * 8);
            acc[js] = __builtin_amdgcn_mfma_f32_16x16x32_bf16(av, bv8, acc[js], 0, 0, 0);
        }
    }
#pragma unroll
    for (int js = 0; js < 4; ++js) {
#pragma unroll
        for (int r = 0; r < 4; ++r) {
            const int tok = row0 + kgrp * 4 + r;
            const int j = nt * 64 + js * 16 + (l & 15);
            const float bias = (j < NE) ? bk[j] : bv[j - NE];
            kvp[(size_t)tok * 1024 + j] = f2bf(acc[js][r] + bias);
        }
    }
}

// w1 -> bw1t bf16 [n][m][hh]
__global__ __launch_bounds__(256) void k_w1t(const float* __restrict__ w1,
                                             bf16_t* __restrict__ bw1t) {
    __shared__ float tile[64][65];
    const int m = blockIdx.x >> 5, n0 = (blockIdx.x & 31) << 6;
    for (int i = threadIdx.x; i < 4096; i += 256) {
        const int hh = i >> 6, nn = i & 63;
        tile[hh][nn] = w1[(size_t)(m * 64 + hh) * ND + n0 + nn];
    }
    __syncthreads();
    for (int i = threadIdx.x; i < 4096; i += 256) {
        const int nn = i >> 6, hh = i & 63;
        bw1t[((size_t)(n0 + nn) * NM + m) * 64 + hh] = f2bf(tile[hh][nn]);
    }
}

__global__ __launch_bounds__(256) void k_w2t(const float* __restrict__ w2,
                                             float* __restrict__ w2t) {
    const int idx = blockIdx.x * 256 + threadIdx.x;
    const int i = idx & 31;
    const int c = (idx >> 5) & 1;
    const int n = idx >> 6;
    w2t[idx] = w2[(size_t)(i * 2 + c) * ND + n];
}

__global__ __launch_bounds__(256) void k_transpose(const float* __restrict__ predTemp,
                                                   float* __restrict__ out) {
    __shared__ float tile[NS * NITER];
    const int b = blockIdx.x >> 6;
    const int j0 = (blockIdx.x & 63) * 64;
    for (int i = threadIdx.x; i < 3200; i += 256) {
        const int tt = i >> 6, jj = i & 63;
        tile[jj * NITER + tt] = predTemp[((size_t)b * NITER + tt) * NOUT + j0 + jj];
    }
    __syncthreads();
    float* dst = out + ((size_t)b * NOUT + j0) * NITER;
    for (int i = threadIdx.x; i < 3200; i += 256) dst[i] = tile[i];
}

extern "C" void kernel_launch(void* const* d_in, const int* in_sizes, int n_in,
                              void* d_out, int out_size, void* d_ws, size_t ws_size,
                              hipStream_t stream) {
    const float* x        = (const float*)d_in[0];
    const float* kv_w     = (const float*)d_in[1];
    const float* kv_b     = (const float*)d_in[2];
    const float* kv_ln_g  = (const float*)d_in[3];
    const float* kv_ln_b  = (const float*)d_in[4];
    const float* q_w      = (const float*)d_in[5];
    const float* q_b      = (const float*)d_in[6];
    const float* wq       = (const float*)d_in[7];
    const float* wk       = (const float*)d_in[8];
    const float* wv       = (const float*)d_in[9];
    const float* wo       = (const float*)d_in[10];
    const float* bq       = (const float*)d_in[11];
    const float* bk       = (const float*)d_in[12];
    const float* bv       = (const float*)d_in[13];
    const float* bo       = (const float*)d_in[14];
    const float* syn_w    = (const float*)d_in[15];
    const float* syn_b    = (const float*)d_in[16];
    const float* syn_ln_g = (const float*)d_in[17];
    const float* syn_ln_b = (const float*)d_in[18];
    const float* nlm1_w   = (const float*)d_in[19];
    const float* nlm1_b   = (const float*)d_in[20];
    const float* nlm2_w   = (const float*)d_in[21];
    const float* nlm2_b   = (const float*)d_in[22];
    const float* start_a  = (const float*)d_in[23];
    const float* start_tr = (const float*)d_in[24];
    const float* dec_a    = (const float*)d_in[25];
    const float* dec_o    = (const float*)d_in[26];
    const float* out_w    = (const float*)d_in[27];
    const float* out_b    = (const float*)d_in[28];
    const int* ial        = (const int*)d_in[29];
    const int* iar        = (const int*)d_in[30];
    const int* iol        = (const int*)d_in[31];
    const int* ior        = (const int*)d_in[32];
    float* out = (float*)d_out;

    float* ws = (float*)d_ws;
    size_t off = 0;
    auto alloc = [&](size_t n) { float* p = ws + off; off += n; return p; };
    float* actT      = alloc((size_t)ND * NB);
    bf16_t* actB     = (bf16_t*)alloc((size_t)NB * NKSYN / 2);
    bf16_t* kvnB     = (bf16_t*)alloc((size_t)NB * NS * NE / 2);
    bf16_t* kvp      = (bf16_t*)alloc((size_t)NB * NS * 1024 / 2);
    bf16_t* wkvpack  = (bf16_t*)alloc((size_t)NE * 1024 / 2);
    bf16_t* W_qqb    = (bf16_t*)alloc((size_t)NE * NE / 2);
    bf16_t* outwp    = (bf16_t*)alloc((size_t)NE * NOUT / 2);
    bf16_t* bwo      = (bf16_t*)alloc((size_t)NE * NE / 2);
    bf16_t* bqw      = (bf16_t*)alloc((size_t)NE * NE / 2);
    bf16_t* synw0p   = (bf16_t*)alloc((size_t)NE * NOUT / 2);
    bf16_t* wqp      = (bf16_t*)alloc((size_t)NE * NE / 2);
    bf16_t* syncB    = (bf16_t*)alloc((size_t)NB * NE / 2);
    float* woSyn     = alloc((size_t)NE * NOUT);
    bf16_t* bpack    = (bf16_t*)alloc((size_t)NKSYN * NOUT / 2);
    float* sbe       = alloc(NOUT);
    float* b_qq      = alloc(NE);
    float* r_a       = alloc(NE);
    float* r_o       = alloc(NE);
    float* statsPart = alloc(512);
    float* aA        = alloc((size_t)2 * NB * NE);      // zero span start
    float* bA        = alloc((size_t)2 * NB * NE);
    float* aO        = alloc((size_t)2 * NB * NE);
    float* bO        = alloc((size_t)2 * NB * NE);
    float* trace2    = alloc((size_t)NM * ND * NB);
    float* part_syn  = alloc((size_t)4 * NB * NOUT);
    float* predRaw   = alloc((size_t)NB * NOUT);
    bf16_t* bw1t     = (bf16_t*)alloc((size_t)ND * NM * 64 / 2);
    float* w2t       = alloc((size_t)ND * 64);
    int tmode = 0;
    float* predTemp = nullptr;
    if ((off + (size_t)PRED_TOTAL) * sizeof(float) <= ws_size) {
        predTemp = alloc((size_t)PRED_TOTAL);
        tmode = 1;
    }

    k_p0<<<9, 256, 0, stream>>>(dec_a, dec_o, q_b, wq, bq, r_a, r_o, b_qq);
    k_cvt<<<(NE * NE) / 256, 256, 0, stream>>>(wo, bwo);
    k_cvt<<<(NE * NE) / 256, 256, 0, stream>>>(q_w, bqw);
    k_packB<<<16 * 64, 256, 0, stream>>>(syn_w, NOUT, 64, 16, synw0p);
    k_packB<<<16 * 8, 256, 0, stream>>>(wq, NE, 8, 16, wqp);
    k_packB<<<16 * 64, 256, 0, stream>>>(out_w, NOUT, 64, 16, outwp);
    k_woSynM<<<512, 256, 0, stream>>>(bwo, synw0p, woSyn);
    k_wqqM<<<64, 256, 0, stream>>>(bqw, wqp, W_qqb);
    k_sbe<<<64, 256, 0, stream>>>(syn_b, bo, syn_w, sbe);
    k_bpack<<<5120, 256, 0, stream>>>(woSyn, syn_w, bpack);
    k_wkvpack<<<256, 256, 0, stream>>>(wk, wv, wkvpack);
    k_init_trace2<<<(NM * ND * NB) / 256, 256, 0, stream>>>(start_tr, trace2);
    k_init_state<<<(INIT_TOTAL + 255) / 256, 256, 0, stream>>>(start_a, actT, actB, aA);
    k_p1a<<<256, 512, 0, stream>>>(x, kv_w, kv_b, kv_ln_g, kv_ln_b, kvnB);
    k_p1b<<<1024, 256, 0, stream>>>(kvnB, wkvpack, bk, bv, kvp);
    k_w1t<<<800, 256, 0, stream>>>(nlm1_w, bw1t);
    k_w2t<<<(ND * 64) / 256, 256, 0, stream>>>(nlm2_w, w2t);

    for (int t = 0; t < NITER; ++t) {
        const int prev = (t > 0) ? 1 : 0;
        k_fo<<<264, 512, 0, stream>>>(actT, actB, aA, bA, r_a, ial, iar, W_qqb, b_qq,
                                      kvp, aO, bO, r_o, iol, ior, syncB,
                                      1, prev, t);
        k_gf<<<320, 256, 0, stream>>>(actB, bpack, part_syn, syncB, outwp, out_b, predRaw,
                                      1, prev);
        k_glu<<<320, 512, 0, stream>>>(part_syn, sbe, trace2, statsPart, t % NM,
                                       predRaw, out, predTemp, 1, prev, t - 1, tmode);
        k_nlm<<<2048, 256, 0, stream>>>(trace2, bw1t, nlm1_b, w2t, nlm2_b, statsPart,
                                        syn_ln_g, syn_ln_b, actT, actB, t % NM);
    }
    // tail: sync(49) -> predRaw(49) -> final(49)
    k_fo<<<264, 512, 0, stream>>>(actT, actB, aA, bA, r_a, ial, iar, W_qqb, b_qq,
                                  kvp, aO, bO, r_o, iol, ior, syncB,
                                  0, 1, NITER);
    k_gf<<<320, 256, 0, stream>>>(actB, bpack, part_syn, syncB, outwp, out_b, predRaw,
                                  0, 1);
    k_glu<<<320, 512, 0, stream>>>(part_syn, sbe, trace2, statsPart, 0,
                                   predRaw, out, predTemp, 0, 1, NITER - 1, tmode);
    if (tmode) k_transpose<<<NB * 64, 256, 0, stream>>>(predTemp, out);
}

// Round 27
// 2814.736 us; speedup vs baseline: 1.0574x; 1.0574x over previous
//
#include <hip/hip_runtime.h>
#include <math.h>

#define NB 64
#define ND 2048
#define NE 512
#define NM 25
#define NOUT 4096
#define NHEADS 8
#define NDH 64
#define NS 64
#define NITER 50
#define NKSYN 2560
#define PRED_TOTAL (NB * NOUT * NITER)   /* 13107200 */

typedef unsigned short bf16_t;
typedef __attribute__((ext_vector_type(8))) short short8;
typedef __attribute__((ext_vector_type(4))) float f32x4;

__device__ __forceinline__ float sigm(float x) { return 1.f / (1.f + expf(-x)); }

__device__ __forceinline__ bf16_t f2bf(float f) {
    unsigned u = __float_as_uint(f);
    unsigned r = (u + 0x7FFFu + ((u >> 16) & 1u)) >> 16;
    return (bf16_t)r;
}
__device__ __forceinline__ float bf2f(bf16_t h) {
    return __uint_as_float(((unsigned)h) << 16);
}

__device__ __forceinline__ float wredsum(float v) {
#pragma unroll
    for (int o = 32; o; o >>= 1) v += __shfl_xor(v, o);
    return v;
}
__device__ __forceinline__ float wredmax(float v) {
#pragma unroll
    for (int o = 32; o; o >>= 1) v = fmaxf(v, __shfl_xor(v, o));
    return v;
}

template <int OP>
__device__ __forceinline__ float blockReduce(float v, float* red) {
    const int tid = threadIdx.x, lane = tid & 63, wid = tid >> 6;
    v = (OP == 0) ? wredsum(v) : wredmax(v);
    __syncthreads();
    if (lane == 0) red[wid] = v;
    __syncthreads();
    if (tid == 0) {
        const int nw = blockDim.x >> 6;
        float r = red[0];
        for (int w = 1; w < nw; ++w) r = (OP == 0) ? r + red[w] : fmaxf(r, red[w]);
        red[0] = r;
    }
    __syncthreads();
    return red[0];
}

// ---------------- per-step kernels (4 dispatches/step) ----------------

// K1: front(t) on blocks [0,256) + sync_o(t-1) on blocks [256,264). 512 thr.
__global__ __launch_bounds__(512) void k_fo(
        const float* __restrict__ actT, bf16_t* __restrict__ actB,
        float* __restrict__ aA, float* __restrict__ bA,
        const float* __restrict__ r_a,
        const int* __restrict__ ial, const int* __restrict__ iar,
        const bf16_t* __restrict__ W_qqb, const float* __restrict__ b_qq,
        const bf16_t* __restrict__ kvp,
        float* __restrict__ aO, float* __restrict__ bO,
        const float* __restrict__ r_o,
        const int* __restrict__ iol, const int* __restrict__ ior,
        bf16_t* __restrict__ syncB,
        int doFront, int doOut, int it) {
    __shared__ float lds[1280];
    const int bid = blockIdx.x;
    const int t = threadIdx.x;
    const int lane = t & 63, wv = t >> 6;

    if (bid >= 256) {
        // ---- sync_o(t-1): 8 blocks, i-slice sb*64, all 64 b ----
        if (!doOut) return;
        const int sb = bid - 256;
        const int itO = it - 1;
        const int srcO = itO & 1, dstO = srcO ^ 1;
#pragma unroll
        for (int c = 0; c < 8; ++c) {
            const int idx = t + c * 512;
            const int il = idx >> 6, bb = idx & 63;
            const int i = sb * 64 + il;
            const float pl = actT[iol[i] * NB + bb];
            const float prr = actT[ior[i] * NB + bb];
            const float r = r_o[i];
            const float aN = r * aO[srcO * 32768 + i * NB + bb] + pl * prr;
            const float bN = r * bO[srcO * 32768 + i * NB + bb] + 1.f;
            aO[dstO * 32768 + i * NB + bb] = aN;
            bO[dstO * 32768 + i * NB + bb] = bN;
            syncB[(size_t)bb * NE + i] = f2bf(aN * rsqrtf(bN));
        }
        return;
    }

    // ---- front(t) ----
    if (!doFront) return;
    float* syncS = lds;
    float* partK = lds + 512;
    float* qhS = lds + 1024;
    float* attnS = lds + 1152;
    const int jt = bid >> 6, b = bid & 63;
    const int src = it & 1, dst = src ^ 1;
    {
        const int i = t;
        const float pl = actT[ial[i] * NB + b];
        const float prr = actT[iar[i] * NB + b];
        const float r = r_a[i];
        const float aN = r * aA[src * 32768 + b * NE + i] + pl * prr;
        const float bN = r * bA[src * 32768 + b * NE + i] + 1.f;
        if (jt == 0) {
            aA[dst * 32768 + b * NE + i] = aN;
            bA[dst * 32768 + b * NE + i] = bN;
        }
        syncS[i] = aN * rsqrtf(bN);
    }
    __syncthreads();
    {
        const int g = t >> 7, l = t & 127;
        const int j = jt * 128 + l;
        float acc = 0.f;
        const int kk0 = g * 128;
#pragma unroll 4
        for (int k = kk0; k < kk0 + 128; ++k)
            acc = fmaf(syncS[k], bf2f(W_qqb[k * NE + j]), acc);
        partK[g * 128 + l] = acc;
    }
    __syncthreads();
    if (t < 128) {
        qhS[t] = b_qq[jt * 128 + t] + partK[t] + partK[128 + t] + partK[256 + t] + partK[384 + t];
    }
    __syncthreads();
    if (wv < 2) {
        const int h = jt * 2 + wv, s = lane;
        const bf16_t* kpp = kvp + ((size_t)(b * NS + s) * 1024 + h * NDH);
        float sc = 0.f;
#pragma unroll 8
        for (int d = 0; d < NDH; ++d) sc = fmaf(qhS[wv * 64 + d], bf2f(kpp[d]), sc);
        sc *= 0.125f;
        const float mxv = wredmax(sc);
        const float ev = expf(sc - mxv);
        const float sm = wredsum(ev);
        attnS[wv * 64 + s] = ev / sm;
    }
    __syncthreads();
    if (wv < 2) {
        const int h = jt * 2 + wv, d = lane;
        const bf16_t* vpp = kvp + ((size_t)(b * NS) * 1024 + NE + h * NDH + d);
        float o = 0.f;
#pragma unroll 8
        for (int s2 = 0; s2 < NS; ++s2) o = fmaf(attnS[wv * 64 + s2], bf2f(vpp[(size_t)s2 * 1024]), o);
        actB[(size_t)b * NKSYN + h * NDH + d] = f2bf(o);
    }
}

// K2: syn MFMA GEMM(t) on blocks [0,512) + out MFMA GEMM(t-1) on [512,576). 256 thr.
__global__ __launch_bounds__(256) void k_gf(
        const bf16_t* __restrict__ actB, const bf16_t* __restrict__ bpack,
        float* __restrict__ part_syn,
        const bf16_t* __restrict__ syncB, const bf16_t* __restrict__ outwp,
        const float* __restrict__ out_b, float* __restrict__ predRaw,
        int doGemm, int doOutM) {
    const int bid = blockIdx.x;
    const int t = threadIdx.x;
    if (bid < 512) {
        if (!doGemm) return;
        const int kp = bid >> 6, jt = bid & 63;
        const int l = t & 63;
        const int wv = t >> 6;
        const int b0 = wv * 16;
        const int row = b0 + (l & 15);
        const int kgrp = l >> 4;
        f32x4 acc[4];
#pragma unroll
        for (int js = 0; js < 4; ++js) acc[js] = (f32x4){0.f, 0.f, 0.f, 0.f};
        const int ks0 = kp * 10;
#pragma unroll 2
        for (int ks = 0; ks < 10; ++ks) {
            const int kk = (ks0 + ks) * 32;
            const short8 av = *(const short8*)(actB + (size_t)row * NKSYN + kk + kgrp * 8);
#pragma unroll
            for (int js = 0; js < 4; ++js) {
                const short8 bv = *(const short8*)(bpack +
                    ((((size_t)(jt * 4 + js)) * 80 + ks0 + ks) * 64 + l) * 8);
                acc[js] = __builtin_amdgcn_mfma_f32_16x16x32_bf16(av, bv, acc[js], 0, 0, 0);
            }
        }
#pragma unroll
        for (int js = 0; js < 4; ++js) {
#pragma unroll
            for (int r = 0; r < 4; ++r) {
                const int b = b0 + kgrp * 4 + r;
                const int j = jt * 64 + js * 16 + (l & 15);
                part_syn[((size_t)(kp * NB + b)) * NOUT + j] = acc[js][r];
            }
        }
    } else {
        // ---- out GEMM(t-1): predRaw[b][j] = syncB @ out_w + out_b. full K=512.
        if (!doOutM) return;
        const int nt = bid - 512;
        const int l = t & 63;
        const int w = t >> 6;
        const int row0 = w * 16;
        const int row = row0 + (l & 15);
        const int kgrp = l >> 4;
        f32x4 acc[4];
#pragma unroll
        for (int js = 0; js < 4; ++js) acc[js] = (f32x4){0.f, 0.f, 0.f, 0.f};
#pragma unroll 2
        for (int ks = 0; ks < 16; ++ks) {
            const short8 av = *(const short8*)(syncB + (size_t)row * NE + ks * 32 + kgrp * 8);
#pragma unroll
            for (int js = 0; js < 4; ++js) {
                const short8 bv8 = *(const short8*)(outwp +
                    ((((size_t)(nt * 4 + js)) * 16 + ks) * 64 + l) * 8);
                acc[js] = __builtin_amdgcn_mfma_f32_16x16x32_bf16(av, bv8, acc[js], 0, 0, 0);
            }
        }
#pragma unroll
        for (int js = 0; js < 4; ++js) {
#pragma unroll
            for (int r = 0; r < 4; ++r) {
                const int b = row0 + kgrp * 4 + r;
                const int j = nt * 64 + js * 16 + (l & 15);
                predRaw[(size_t)b * NOUT + j] = acc[js][r] + out_b[j];
            }
        }
    }
}

// K3: glu on blocks [0,256) + final(t-1) on blocks [256,320). 512 thr.
// Writes raw g to gRaw (fp32); normalization + ring write happen in k_nlm.
__global__ __launch_bounds__(512) void k_glu(const float* __restrict__ part,
                                             const float* __restrict__ sbe,
                                             float* __restrict__ gRaw,
                                             float* __restrict__ statsPart,
                                             const float* __restrict__ predRaw,
                                             float* __restrict__ out,
                                             float* __restrict__ predTemp,
                                             int doGlu, int doFinal, int tt, int tmode) {
    __shared__ float red[8];
    const int bid = blockIdx.x;
    const int t = threadIdx.x;
    if (bid < 256) {
        if (!doGlu) return;
        const int b = bid >> 2, q = bid & 3;
        const int n = q * 512 + t;
        float ya = sbe[n], yb = sbe[n + ND];
#pragma unroll
        for (int kp = 0; kp < 8; ++kp) {
            ya += part[((size_t)(kp * NB + b)) * NOUT + n];
            yb += part[((size_t)(kp * NB + b)) * NOUT + n + ND];
        }
        const float g = ya * sigm(yb);
        gRaw[(size_t)n * NB + b] = g;                    // raw (normalized by k_nlm)
        const float s = blockReduce<0>(g, red);
        const float ss = blockReduce<0>(g * g, red);
        if (t == 0) {
            statsPart[bid * 2 + 0] = s;
            statsPart[bid * 2 + 1] = ss;
        }
    } else {
        if (!doFinal) return;
        const int b = bid - 256;
        float pr[8];
        float lmax = -1e30f;
#pragma unroll
        for (int c = 0; c < 8; ++c) {
            const int j = t + c * 512;
            const float v = predRaw[(size_t)b * NOUT + j];
            pr[c] = v;
            lmax = fmaxf(lmax, v);
        }
        const float mx = blockReduce<1>(lmax, red);
        float ls = 0.f;
#pragma unroll
        for (int c = 0; c < 8; ++c) ls += expf(pr[c] - mx);
        const float se = blockReduce<0>(ls, red);
        const float logZ = mx + logf(se);
        float le = 0.f;
#pragma unroll
        for (int c = 0; c < 8; ++c) { const float lp = pr[c] - logZ; le += expf(lp) * lp; }
        const float ent = blockReduce<0>(le, red);
        const float ne = -ent * 0.12022458674074694f;  // 1/ln(4096)
        if (tmode) {
#pragma unroll
            for (int c = 0; c < 8; ++c)
                predTemp[((size_t)b * NITER + tt) * NOUT + t + c * 512] = pr[c];
        } else {
#pragma unroll
            for (int c = 0; c < 8; ++c) {
                const int j = t + c * 512;
                out[((size_t)b * NOUT + j) * NITER + tt] = pr[c];
            }
        }
        if (t == 0) {
            out[PRED_TOTAL + b * 100 + tt] = ne;
            out[PRED_TOTAL + b * 100 + 50 + tt] = 1.f - ne;
        }
    }
}

// K4: per-neuron NLMs, block = ONE neuron (grid 2048 x 256). Trace ring is
// bf16 (traceB); raw newest value comes from gRaw fp32 and is used at full
// precision in-step. Ring write slot (pos) is disjoint from read slots
// (pos+1..pos+24) -> no intra-block race.
__global__ __launch_bounds__(256) void k_nlm(bf16_t* __restrict__ traceB,
                                             const float* __restrict__ gRaw,
                                             const bf16_t* __restrict__ bw1t,
                                             const float* __restrict__ b1,
                                             const float* __restrict__ w2t,
                                             const float* __restrict__ b2,
                                             const float* __restrict__ statsPart,
                                             const float* __restrict__ ln_g,
                                             const float* __restrict__ ln_b,
                                             float* __restrict__ actT,
                                             bf16_t* __restrict__ actB, int pos) {
    __shared__ float sacc[32][64];
    __shared__ float pz[2][2][64];
    const int b = threadIdx.x & 63;
    const int g = __builtin_amdgcn_readfirstlane(threadIdx.x >> 6);
    const int n = blockIdx.x;
    const int hh0 = g * 16;
    float ssum = 0.f, ssq = 0.f;
#pragma unroll
    for (int q = 0; q < 4; ++q) {
        ssum += statsPart[(b * 4 + q) * 2 + 0];
        ssq  += statsPart[(b * 4 + q) * 2 + 1];
    }
    const float mean = ssum * (1.f / ND);
    const float rs = rsqrtf(ssq * (1.f / ND) - mean * mean + 1e-5f);

    float trv[NM];
    {
        int phys = (pos + 1 < NM) ? pos + 1 : 0;
#pragma unroll
        for (int m = 0; m < NM - 1; ++m) {
            trv[m] = bf2f(traceB[((size_t)phys * ND + n) * NB + b]);
            phys = (phys + 1 < NM) ? phys + 1 : 0;
        }
        const float raw = gRaw[(size_t)n * NB + b];
        const float trNew = (raw - mean) * rs * ln_g[n] + ln_b[n];
        trv[NM - 1] = trNew;
        if (g == 0) traceB[((size_t)pos * ND + n) * NB + b] = f2bf(trNew);
    }

    float acc[16];
    {
        const float* brow = b1 + n * 64 + hh0;
#pragma unroll
        for (int q = 0; q < 16; ++q) acc[q] = brow[q];
    }
#pragma unroll
    for (int m = 0; m < NM; ++m) {
        const float tr = trv[m];
        const unsigned* wrow = (const unsigned*)(bw1t + ((size_t)n * NM + m) * 64 + hh0);
#pragma unroll
        for (int q = 0; q < 8; ++q) {
            const unsigned u = wrow[q];
            const float w0 = __uint_as_float(u << 16);
            const float w1 = __uint_as_float(u & 0xffff0000u);
            acc[2 * q + 0] = fmaf(tr, w0, acc[2 * q + 0]);
            acc[2 * q + 1] = fmaf(tr, w1, acc[2 * q + 1]);
        }
    }
    if (g >= 2) {
#pragma unroll
        for (int q = 0; q < 16; ++q) sacc[hh0 - 32 + q][b] = acc[q];
    }
    __syncthreads();
    if (g < 2) {
        const float* w2r = w2t + n * 64;
        float z0p = 0.f, z1p = 0.f;
#pragma unroll
        for (int q = 0; q < 16; ++q) {
            const int i = hh0 + q;
            const float hv = acc[q] * sigm(sacc[i][b]);
            z0p = fmaf(hv, w2r[i], z0p);
            z1p = fmaf(hv, w2r[32 + i], z1p);
        }
        pz[0][g][b] = z0p;
        pz[1][g][b] = z1p;
    }
    __syncthreads();
    if (g == 0) {
        const float z0 = b2[n * 2 + 0] + pz[0][0][b] + pz[0][1][b];
        const float z1 = b2[n * 2 + 1] + pz[1][0][b] + pz[1][1][b];
        const float val = z0 * sigm(z1);
        actT[n * NB + b] = val;
        actB[(size_t)b * NKSYN + NE + n] = f2bf(val);
    }
}

// ---------------- one-time precompute kernels ----------------

__global__ __launch_bounds__(256) void k_p0(const float* __restrict__ dec_a,
                                            const float* __restrict__ dec_o,
                                            const float* __restrict__ q_b,
                                            const float* __restrict__ wq,
                                            const float* __restrict__ bq,
                                            float* __restrict__ r_a, float* __restrict__ r_o,
                                            float* __restrict__ b_qq) {
    const int t = threadIdx.x;
    if (blockIdx.x == 0) {
        for (int i = t; i < NE; i += 256) {
            r_a[i] = expf(-fminf(fmaxf(dec_a[i], 0.f), 15.f));
            r_o[i] = expf(-fminf(fmaxf(dec_o[i], 0.f), 15.f));
        }
        return;
    }
    __shared__ float partial[4][64];
    const int c = (blockIdx.x - 1) * 64 + (t & 63);
    const int kg = t >> 6;
    float acc = 0.f;
#pragma unroll 4
    for (int k = kg * 128; k < kg * 128 + 128; ++k)
        acc = fmaf(q_b[k], wq[k * NE + c], acc);
    partial[kg][t & 63] = acc;
    __syncthreads();
    if (t < 64) {
        const int cc = (blockIdx.x - 1) * 64 + t;
        b_qq[cc] = bq[cc] + partial[0][t] + partial[1][t] + partial[2][t] + partial[3][t];
    }
}

// Generic B-fragment pack: src [K x ld] fp32 -> MFMA frag order.
__global__ __launch_bounds__(256) void k_packB(const float* __restrict__ src,
                                               int ld, int nbj, int ksgs,
                                               bf16_t* __restrict__ dst) {
    __shared__ float tile[32][65];
    const int ksg = blockIdx.x / nbj;
    const int bj = blockIdx.x % nbj;
    const int k0 = ksg * 32, j0 = bj * 64;
    for (int i = threadIdx.x; i < 2048; i += 256) {
        const int kk = i >> 6, jj = i & 63;
        tile[kk][jj] = src[(size_t)(k0 + kk) * ld + j0 + jj];
    }
    __syncthreads();
    for (int i = threadIdx.x; i < 2048; i += 256) {
        const int j16 = i >> 9;
        const int ii = i & 511;
        const int e = ii & 7, l = ii >> 3;
        const int kk = (l >> 4) * 8 + e;
        const int jj = j16 * 16 + (l & 15);
        dst[(((size_t)(bj * 4 + j16) * ksgs + ksg) * 64) * 8 + ii] = f2bf(tile[kk][jj]);
    }
}

// woSyn = wo @ syn_w[0:512] via MFMA. grid 512 (mt 8 x nt 64) x 256. fp32 out.
__global__ __launch_bounds__(256, 2) void k_woSynM(const bf16_t* __restrict__ bwo,
                                                   const bf16_t* __restrict__ synw0p,
                                                   float* __restrict__ woSyn) {
    const int mt = blockIdx.x >> 6, nt = blockIdx.x & 63;
    const int l = threadIdx.x & 63;
    const int w = threadIdx.x >> 6;
    const int row0 = mt * 64 + w * 16;
    const int row = row0 + (l & 15);
    const int kgrp = l >> 4;
    f32x4 acc[4];
#pragma unroll
    for (int js = 0; js < 4; ++js) acc[js] = (f32x4){0.f, 0.f, 0.f, 0.f};
#pragma unroll 2
    for (int ks = 0; ks < 16; ++ks) {
        const short8 av = *(const short8*)(bwo + (size_t)row * NE + ks * 32 + kgrp * 8);
#pragma unroll
        for (int js = 0; js < 4; ++js) {
            const short8 bv8 = *(const short8*)(synw0p +
                ((((size_t)(nt * 4 + js)) * 16 + ks) * 64 + l) * 8);
            acc[js] = __builtin_amdgcn_mfma_f32_16x16x32_bf16(av, bv8, acc[js], 0, 0, 0);
        }
    }
#pragma unroll
    for (int js = 0; js < 4; ++js) {
#pragma unroll
        for (int r = 0; r < 4; ++r) {
            const int e = row0 + kgrp * 4 + r;
            const int c = nt * 64 + js * 16 + (l & 15);
            woSyn[(size_t)e * NOUT + c] = acc[js][r];
        }
    }
}

// W_qq = q_w @ wq via MFMA -> bf16. grid 64 (mt 8 x nt 8) x 256.
__global__ __launch_bounds__(256, 2) void k_wqqM(const bf16_t* __restrict__ bqw,
                                                 const bf16_t* __restrict__ wqp,
                                                 bf16_t* __restrict__ W_qqb) {
    const int mt = blockIdx.x >> 3, nt = blockIdx.x & 7;
    const int l = threadIdx.x & 63;
    const int w = threadIdx.x >> 6;
    const int row0 = mt * 64 + w * 16;
    const int row = row0 + (l & 15);
    const int kgrp = l >> 4;
    f32x4 acc[4];
#pragma unroll
    for (int js = 0; js < 4; ++js) acc[js] = (f32x4){0.f, 0.f, 0.f, 0.f};
#pragma unroll 2
    for (int ks = 0; ks < 16; ++ks) {
        const short8 av = *(const short8*)(bqw + (size_t)row * NE + ks * 32 + kgrp * 8);
#pragma unroll
        for (int js = 0; js < 4; ++js) {
            const short8 bv8 = *(const short8*)(wqp +
                ((((size_t)(nt * 4 + js)) * 16 + ks) * 64 + l) * 8);
            acc[js] = __builtin_amdgcn_mfma_f32_16x16x32_bf16(av, bv8, acc[js], 0, 0, 0);
        }
    }
#pragma unroll
    for (int js = 0; js < 4; ++js) {
#pragma unroll
        for (int r = 0; r < 4; ++r) {
            const int e = row0 + kgrp * 4 + r;
            const int c = nt * 64 + js * 16 + (l & 15);
            W_qqb[(size_t)e * NE + c] = f2bf(acc[js][r]);
        }
    }
}

// sbe: grid 64 x 256, 4-way k-split + LDS reduce.
__global__ __launch_bounds__(256) void k_sbe(const float* __restrict__ syn_b,
                                             const float* __restrict__ bo,
                                             const float* __restrict__ syn_w,
                                             float* __restrict__ sbe) {
    __shared__ float partial[4][64];
    const int c = blockIdx.x * 64 + (threadIdx.x & 63);
    const int kg = threadIdx.x >> 6;
    float acc = 0.f;
#pragma unroll 4
    for (int jp = kg * 128; jp < kg * 128 + 128; ++jp)
        acc = fmaf(bo[jp], syn_w[(size_t)jp * NOUT + c], acc);
    partial[kg][threadIdx.x & 63] = acc;
    __syncthreads();
    if (threadIdx.x < 64) {
        const int cc = blockIdx.x * 64 + threadIdx.x;
        sbe[cc] = syn_b[cc] + partial[0][threadIdx.x] + partial[1][threadIdx.x]
                + partial[2][threadIdx.x] + partial[3][threadIdx.x];
    }
}

__global__ __launch_bounds__(256) void k_cvt(const float* __restrict__ s,
                                             bf16_t* __restrict__ d) {
    const size_t i = (size_t)blockIdx.x * 256 + threadIdx.x;
    d[i] = f2bf(s[i]);
}

// Tiled fragment-pack of combined weights [woSyn rows<512; syn_w rows 512+].
__global__ __launch_bounds__(256) void k_bpack(const float* __restrict__ woSyn,
                                               const float* __restrict__ syn_w,
                                               bf16_t* __restrict__ bpack) {
    __shared__ float tile[32][65];
    const int ksg = blockIdx.x >> 6;
    const int bj = blockIdx.x & 63;
    const int k0 = ksg * 32, j0 = bj * 64;
    for (int i = threadIdx.x; i < 2048; i += 256) {
        const int kk = i >> 6, jj = i & 63;
        const int k = k0 + kk;
        tile[kk][jj] = (k < NE) ? woSyn[(size_t)k * NOUT + j0 + jj]
                                : syn_w[(size_t)k * NOUT + j0 + jj];
    }
    __syncthreads();
    for (int i = threadIdx.x; i < 2048; i += 256) {
        const int j16 = i >> 9;
        const int ii = i & 511;
        const int e = ii & 7, l = ii >> 3;
        const int kk = (l >> 4) * 8 + e;
        const int jj = j16 * 16 + (l & 15);
        bpack[(((size_t)(bj * 4 + j16) * 80 + ksg) * 64) * 8 + ii] = f2bf(tile[kk][jj]);
    }
}

// Pack [wk | wv] (512 x 1024) into MFMA B-fragment order. grid 256.
__global__ __launch_bounds__(256) void k_wkvpack(const float* __restrict__ wk,
                                                 const float* __restrict__ wv,
                                                 bf16_t* __restrict__ wkvpack) {
    __shared__ float tile[32][65];
    const int ksg = blockIdx.x >> 4;
    const int bj = blockIdx.x & 15;
    const int k0 = ksg * 32, j0 = bj * 64;
    for (int i = threadIdx.x; i < 2048; i += 256) {
        const int kk = i >> 6, jj = i & 63;
        const int k = k0 + kk, j = j0 + jj;
        tile[kk][jj] = (j < NE) ? wk[(size_t)k * NE + j] : wv[(size_t)k * NE + (j - NE)];
    }
    __syncthreads();
    for (int i = threadIdx.x; i < 2048; i += 256) {
        const int j16 = i >> 9;
        const int ii = i & 511;
        const int e = ii & 7, l = ii >> 3;
        const int kk = (l >> 4) * 8 + e;
        const int jj = j16 * 16 + (l & 15);
        wkvpack[(((size_t)(bj * 4 + j16) * 16 + ksg) * 64) * 8 + ii] = f2bf(tile[kk][jj]);
    }
}

__global__ __launch_bounds__(256) void k_init_trace2(const float* __restrict__ st,
                                                     bf16_t* __restrict__ traceB) {
    const int idx = blockIdx.x * 256 + threadIdx.x;
    const int n = (idx >> 6) & (ND - 1);
    const int m = idx >> 17;
    traceB[idx] = f2bf(st[n * NM + m]);
}

#define INIT_TOTAL (NB * ND + 8 * NB * NE)
__global__ __launch_bounds__(256) void k_init_state(const float* __restrict__ sa,
                                                    float* __restrict__ actT,
                                                    bf16_t* __restrict__ actB,
                                                    float* __restrict__ zeroBase) {
    const int idx = blockIdx.x * 256 + threadIdx.x;
    if (idx >= INIT_TOTAL) return;
    if (idx < NB * ND) {
        const int b = idx & 63, n = idx >> 6;
        actT[n * NB + b] = sa[n];
        actB[(size_t)b * NKSYN + NE + n] = f2bf(sa[n]);
    } else {
        zeroBase[idx - NB * ND] = 0.f;
    }
}

// k_p1a: kvn = LN(feats @ kv_w + kv_b) -> kvnB bf16 [token][e].
__global__ __launch_bounds__(512) void k_p1a(const float* __restrict__ x,
                                             const float* __restrict__ kv_w,
                                             const float* __restrict__ kv_b,
                                             const float* __restrict__ ln_g,
                                             const float* __restrict__ ln_b,
                                             bf16_t* __restrict__ kvnB) {
    __shared__ float kvT[NE][17];
    __shared__ float mS[16], rS[16];
    const int b = blockIdx.x >> 2, s0 = (blockIdx.x & 3) * 16;
    const int t = threadIdx.x;
    const int lane = t & 63, wvi = t >> 6;
    {
        float w[12];
#pragma unroll
        for (int c = 0; c < 12; ++c) w[c] = kv_w[c * NE + t];
        const float kb = kv_b[t];
#pragma unroll
        for (int tok = 0; tok < 16; ++tok) {
            float acc = kb;
#pragma unroll
            for (int c = 0; c < 12; ++c)
                acc = fmaf(x[b * 768 + c * 64 + s0 + tok], w[c], acc);
            kvT[t][tok] = acc;
        }
    }
    __syncthreads();
#pragma unroll
    for (int q = 0; q < 2; ++q) {
        const int tok = wvi * 2 + q;
        float s = 0.f, ss = 0.f;
#pragma unroll
        for (int i = 0; i < 8; ++i) {
            const float v = kvT[lane + 64 * i][tok];
            s += v; ss = fmaf(v, v, ss);
        }
        s = wredsum(s); ss = wredsum(ss);
        if (lane == 0) {
            const float mean = s * (1.f / NE);
            mS[tok] = mean;
            rS[tok] = rsqrtf(ss * (1.f / NE) - mean * mean + 1e-5f);
        }
    }
    __syncthreads();
    {
        const float g = ln_g[t], bb2 = ln_b[t];
#pragma unroll
        for (int tok = 0; tok < 16; ++tok) {
            const float kvn = (kvT[t][tok] - mS[tok]) * rS[tok] * g + bb2;
            kvnB[(size_t)(b * 64 + s0 + tok) * NE + t] = f2bf(kvn);
        }
    }
}

// k_p1b: MFMA GEMM [4096 tokens x 1024 (K|V) x 512] -> kvp bf16 [token][1024].
__global__ __launch_bounds__(256, 2) void k_p1b(const bf16_t* __restrict__ kvnB,
                                                const bf16_t* __restrict__ wkvpack,
                                                const float* __restrict__ bk,
                                                const float* __restrict__ bv,
                                                bf16_t* __restrict__ kvp) {
    const int mt = blockIdx.x >> 4, nt = blockIdx.x & 15;
    const int l = threadIdx.x & 63;
    const int wv = threadIdx.x >> 6;
    const int row0 = mt * 64 + wv * 16;
    const int row = row0 + (l & 15);
    const int kgrp = l >> 4;
    f32x4 acc[4];
#pragma unroll
    for (int js = 0; js < 4; ++js) acc[js] = (f32x4){0.f, 0.f, 0.f, 0.f};
#pragma unroll 2
    for (int ks = 0; ks < 16; ++ks) {
        const short8 av = *(const short8*)(kvnB + (size_t)row * NE + ks * 32 + kgrp * 8);
#pragma unroll
        for (int js = 0; js < 4; ++js) {
            const short8 bv8 = *(const short8*)(wkvpack +
                ((((size_t)(nt * 4 + js)) * 16 + ks) * 64 + l) * 8);
            acc[js] = __builtin_amdgcn_mfma_f32_16x16x32_bf16(av, bv8, acc[js], 0, 0, 0);
        }
    }
#pragma unroll
    for (int js = 0; js < 4; ++js) {
#pragma unroll
        for (int r = 0; r < 4; ++r) {
            const int tok = row0 + kgrp * 4 + r;
            const int j = nt * 64 + js * 16 + (l & 15);
            const float bias = (j < NE) ? bk[j] : bv[j - NE];
            kvp[(size_t)tok * 1024 + j] = f2bf(acc[js][r] + bias);
        }
    }
}

// w1 -> bw1t bf16 [n][m][hh]
__global__ __launch_bounds__(256) void k_w1t(const float* __restrict__ w1,
                                             bf16_t* __restrict__ bw1t) {
    __shared__ float tile[64][65];
    const int m = blockIdx.x >> 5, n0 = (blockIdx.x & 31) << 6;
    for (int i = threadIdx.x; i < 4096; i += 256) {
        const int hh = i >> 6, nn = i & 63;
        tile[hh][nn] = w1[(size_t)(m * 64 + hh) * ND + n0 + nn];
    }
    __syncthreads();
    for (int i = threadIdx.x; i < 4096; i += 256) {
        const int nn = i >> 6, hh = i & 63;
        bw1t[((size_t)(n0 + nn) * NM + m) * 64 + hh] = f2bf(tile[hh][nn]);
    }
}

__global__ __launch_bounds__(256) void k_w2t(const float* __restrict__ w2,
                                             float* __restrict__ w2t) {
    const int idx = blockIdx.x * 256 + threadIdx.x;
    const int i = idx & 31;
    const int c = (idx >> 5) & 1;
    const int n = idx >> 6;
    w2t[idx] = w2[(size_t)(i * 2 + c) * ND + n];
}

__global__ __launch_bounds__(256) void k_transpose(const float* __restrict__ predTemp,
                                                   float* __restrict__ out) {
    __shared__ float tile[NS * NITER];
    const int b = blockIdx.x >> 6;
    const int j0 = (blockIdx.x & 63) * 64;
    for (int i = threadIdx.x; i < 3200; i += 256) {
        const int tt = i >> 6, jj = i & 63;
        tile[jj * NITER + tt] = predTemp[((size_t)b * NITER + tt) * NOUT + j0 + jj];
    }
    __syncthreads();
    float* dst = out + ((size_t)b * NOUT + j0) * NITER;
    for (int i = threadIdx.x; i < 3200; i += 256) dst[i] = tile[i];
}

extern "C" void kernel_launch(void* const* d_in, const int* in_sizes, int n_in,
                              void* d_out, int out_size, void* d_ws, size_t ws_size,
                              hipStream_t stream) {
    const float* x        = (const float*)d_in[0];
    const float* kv_w     = (const float*)d_in[1];
    const float* kv_b     = (const float*)d_in[2];
    const float* kv_ln_g  = (const float*)d_in[3];
    const float* kv_ln_b  = (const float*)d_in[4];
    const float* q_w      = (const float*)d_in[5];
    const float* q_b      = (const float*)d_in[6];
    const float* wq       = (const float*)d_in[7];
    const float* wk       = (const float*)d_in[8];
    const float* wv       = (const float*)d_in[9];
    const float* wo       = (const float*)d_in[10];
    const float* bq       = (const float*)d_in[11];
    const float* bk       = (const float*)d_in[12];
    const float* bv       = (const float*)d_in[13];
    const float* bo       = (const float*)d_in[14];
    const float* syn_w    = (const float*)d_in[15];
    const float* syn_b    = (const float*)d_in[16];
    const float* syn_ln_g = (const float*)d_in[17];
    const float* syn_ln_b = (const float*)d_in[18];
    const float* nlm1_w   = (const float*)d_in[19];
    const float* nlm1_b   = (const float*)d_in[20];
    const float* nlm2_w   = (const float*)d_in[21];
    const float* nlm2_b   = (const float*)d_in[22];
    const float* start_a  = (const float*)d_in[23];
    const float* start_tr = (const float*)d_in[24];
    const float* dec_a    = (const float*)d_in[25];
    const float* dec_o    = (const float*)d_in[26];
    const float* out_w    = (const float*)d_in[27];
    const float* out_b    = (const float*)d_in[28];
    const int* ial        = (const int*)d_in[29];
    const int* iar        = (const int*)d_in[30];
    const int* iol        = (const int*)d_in[31];
    const int* ior        = (const int*)d_in[32];
    float* out = (float*)d_out;

    float* ws = (float*)d_ws;
    size_t off = 0;
    auto alloc = [&](size_t n) { float* p = ws + off; off += n; return p; };
    float* actT      = alloc((size_t)ND * NB);
    bf16_t* actB     = (bf16_t*)alloc((size_t)NB * NKSYN / 2);
    bf16_t* kvnB     = (bf16_t*)alloc((size_t)NB * NS * NE / 2);
    bf16_t* kvp      = (bf16_t*)alloc((size_t)NB * NS * 1024 / 2);
    bf16_t* wkvpack  = (bf16_t*)alloc((size_t)NE * 1024 / 2);
    bf16_t* W_qqb    = (bf16_t*)alloc((size_t)NE * NE / 2);
    bf16_t* outwp    = (bf16_t*)alloc((size_t)NE * NOUT / 2);
    bf16_t* bwo      = (bf16_t*)alloc((size_t)NE * NE / 2);
    bf16_t* bqw      = (bf16_t*)alloc((size_t)NE * NE / 2);
    bf16_t* synw0p   = (bf16_t*)alloc((size_t)NE * NOUT / 2);
    bf16_t* wqp      = (bf16_t*)alloc((size_t)NE * NE / 2);
    bf16_t* syncB    = (bf16_t*)alloc((size_t)NB * NE / 2);
    float* woSyn     = alloc((size_t)NE * NOUT);
    bf16_t* bpack    = (bf16_t*)alloc((size_t)NKSYN * NOUT / 2);
    float* sbe       = alloc(NOUT);
    float* b_qq      = alloc(NE);
    float* r_a       = alloc(NE);
    float* r_o       = alloc(NE);
    float* statsPart = alloc(512);
    float* aA        = alloc((size_t)2 * NB * NE);      // zero span start
    float* bA        = alloc((size_t)2 * NB * NE);
    float* aO        = alloc((size_t)2 * NB * NE);
    float* bO        = alloc((size_t)2 * NB * NE);
    bf16_t* traceB   = (bf16_t*)alloc((size_t)NM * ND * NB / 2);
    float* gRaw      = alloc((size_t)ND * NB);
    float* part_syn  = alloc((size_t)8 * NB * NOUT);
    float* predRaw   = alloc((size_t)NB * NOUT);
    bf16_t* bw1t     = (bf16_t*)alloc((size_t)ND * NM * 64 / 2);
    float* w2t       = alloc((size_t)ND * 64);
    int tmode = 0;
    float* predTemp = nullptr;
    if ((off + (size_t)PRED_TOTAL) * sizeof(float) <= ws_size) {
        predTemp = alloc((size_t)PRED_TOTAL);
        tmode = 1;
    }

    k_p0<<<9, 256, 0, stream>>>(dec_a, dec_o, q_b, wq, bq, r_a, r_o, b_qq);
    k_cvt<<<(NE * NE) / 256, 256, 0, stream>>>(wo, bwo);
    k_cvt<<<(NE * NE) / 256, 256, 0, stream>>>(q_w, bqw);
    k_packB<<<16 * 64, 256, 0, stream>>>(syn_w, NOUT, 64, 16, synw0p);
    k_packB<<<16 * 8, 256, 0, stream>>>(wq, NE, 8, 16, wqp);
    k_packB<<<16 * 64, 256, 0, stream>>>(out_w, NOUT, 64, 16, outwp);
    k_woSynM<<<512, 256, 0, stream>>>(bwo, synw0p, woSyn);
    k_wqqM<<<64, 256, 0, stream>>>(bqw, wqp, W_qqb);
    k_sbe<<<64, 256, 0, stream>>>(syn_b, bo, syn_w, sbe);
    k_bpack<<<5120, 256, 0, stream>>>(woSyn, syn_w, bpack);
    k_wkvpack<<<256, 256, 0, stream>>>(wk, wv, wkvpack);
    k_init_trace2<<<(NM * ND * NB) / 256, 256, 0, stream>>>(start_tr, traceB);
    k_init_state<<<(INIT_TOTAL + 255) / 256, 256, 0, stream>>>(start_a, actT, actB, aA);
    k_p1a<<<256, 512, 0, stream>>>(x, kv_w, kv_b, kv_ln_g, kv_ln_b, kvnB);
    k_p1b<<<1024, 256, 0, stream>>>(kvnB, wkvpack, bk, bv, kvp);
    k_w1t<<<800, 256, 0, stream>>>(nlm1_w, bw1t);
    k_w2t<<<(ND * 64) / 256, 256, 0, stream>>>(nlm2_w, w2t);

    for (int t = 0; t < NITER; ++t) {
        const int prev = (t > 0) ? 1 : 0;
        k_fo<<<264, 512, 0, stream>>>(actT, actB, aA, bA, r_a, ial, iar, W_qqb, b_qq,
                                      kvp, aO, bO, r_o, iol, ior, syncB,
                                      1, prev, t);
        k_gf<<<576, 256, 0, stream>>>(actB, bpack, part_syn, syncB, outwp, out_b, predRaw,
                                      1, prev);
        k_glu<<<320, 512, 0, stream>>>(part_syn, sbe, gRaw, statsPart,
                                       predRaw, out, predTemp, 1, prev, t - 1, tmode);
        k_nlm<<<2048, 256, 0, stream>>>(traceB, gRaw, bw1t, nlm1_b, w2t, nlm2_b, statsPart,
                                        syn_ln_g, syn_ln_b, actT, actB, t % NM);
    }
    // tail: sync(49) -> predRaw(49) -> final(49)
    k_fo<<<264, 512, 0, stream>>>(actT, actB, aA, bA, r_a, ial, iar, W_qqb, b_qq,
                                  kvp, aO, bO, r_o, iol, ior, syncB,
                                  0, 1, NITER);
    k_gf<<<576, 256, 0, stream>>>(actB, bpack, part_syn, syncB, outwp, out_b, predRaw,
                                  0, 1);
    k_glu<<<320, 512, 0, stream>>>(part_syn, sbe, gRaw, statsPart,
                                   predRaw, out, predTemp, 0, 1, NITER - 1, tmode);
    if (tmode) k_transpose<<<NB * 64, 256, 0, stream>>>(predTemp, out);
}